// Round 5
// baseline (476.360 us; speedup 1.0000x reference)
//
#include <hip/hip_runtime.h>
#include <math.h>

// B=4, S=4096 -> 16384 tokens; H=4096; E=64; TOP_K=2
#define TOKENS 16384
#define HDIM 4096
#define NE 64

#define BM 64   // tokens per block
#define LP 68   // logits LDS row stride (floats)

typedef float f32x4 __attribute__((ext_vector_type(4)));
typedef int i32x4 __attribute__((ext_vector_type(4)));
typedef __bf16 bf16x8 __attribute__((ext_vector_type(8)));

// f32 -> (hi, lo) bf16 split of 8 elements; each packed as 4xint = 8 bf16.
// a ~= hi + lo with residual ~2^-18|a| -> 3-term MFMA reproduces ~f32 accuracy.
__device__ __forceinline__ void split8(f32x4 v0, f32x4 v1, i32x4& h, i32x4& l) {
  float x[8];
#pragma unroll
  for (int j = 0; j < 4; ++j) { x[j] = v0[j]; x[4 + j] = v1[j]; }
  union { unsigned short u[8]; i32x4 v; } H, L;
#pragma unroll
  for (int j = 0; j < 8; ++j) {
    __bf16 hb = (__bf16)x[j];
    H.u[j] = __builtin_bit_cast(unsigned short, hb);
    L.u[j] = __builtin_bit_cast(unsigned short, (__bf16)(x[j] - (float)hb));
  }
  h = H.v; l = L.v;
}

__device__ __forceinline__ f32x4 mfma_bf16(i32x4 a, i32x4 b, f32x4 c) {
  return __builtin_amdgcn_mfma_f32_16x16x32_bf16(
      __builtin_bit_cast(bf16x8, a), __builtin_bit_cast(bf16x8, b), c, 0, 0, 0);
}

// Pre-split W (64x4096 f32 -> bf16 hi/lo in workspace). ~2 us once. (verified)
__global__ __launch_bounds__(256) void convert_w(const float* __restrict__ W,
                                                 unsigned short* __restrict__ Wh,
                                                 unsigned short* __restrict__ Wl) {
  const int i = (blockIdx.x * 256 + threadIdx.x) * 8;
  f32x4 v0 = *(const f32x4*)(W + i);
  f32x4 v1 = *(const f32x4*)(W + i + 4);
  i32x4 h, l;
  split8(v0, v1, h, l);
  *(i32x4*)(Wh + i) = h;
  *(i32x4*)(Wl + i) = l;
}

// Barrier-free fused router. The 16x16x32 MFMA fragment (m89 layout: lane l
// holds X[l&15][(l>>4)*8+j]) is 8 CONSECUTIVE k-elements of one row -> both
// operands load directly from global (A: 32 B/lane f32, W: 16 B/lane bf16).
// No LDS staging, no K-loop __syncthreads: 8 independent wave-streams per CU,
// compiler pipelines loads across unrolled k-steps, no barrier convergence.
// W re-read per block is L2-served; A's eg-duplicate read hits L1.
// Wave wv: tg=wv&3 -> 16-token group, eg=wv>>2 -> 32-expert half (2 tiles).
__global__ __launch_bounds__(512, 2) void router_mfma(const float* __restrict__ A,
                                                      const unsigned short* __restrict__ Wh,
                                                      const unsigned short* __restrict__ Wl,
                                                      float* __restrict__ out) {
  __shared__ __align__(16) float L[BM * LP];  // 17 KiB logits tile (epilogue only)

  const int tid = threadIdx.x;
  const int bt = blockIdx.x;
  const int lane = tid & 63;
  const int wv = tid >> 6;
  const int tg = wv & 3;
  const int eg = wv >> 2;
  const int l15 = lane & 15;
  const int fko = lane >> 4;  // k-subgroup 0..3

  // per-lane fragment base pointers (8 consecutive k-elements each)
  const float* Ap = A + (size_t)(bt * BM + tg * 16 + l15) * HDIM + fko * 8;
  const unsigned short* Wh0 = Wh + (size_t)(eg * 32 + l15) * HDIM + fko * 8;
  const unsigned short* Wl0 = Wl + (size_t)(eg * 32 + l15) * HDIM + fko * 8;
  const unsigned short* Wh1 = Wh0 + 16 * HDIM;  // second 16-expert tile
  const unsigned short* Wl1 = Wl0 + 16 * HDIM;

  f32x4 acc0 = {0.f, 0.f, 0.f, 0.f};
  f32x4 acc1 = {0.f, 0.f, 0.f, 0.f};

#pragma unroll 2
  for (int kc = 0; kc < HDIM; kc += 32) {
    f32x4 a0 = *(const f32x4*)(Ap + kc);
    f32x4 a1 = *(const f32x4*)(Ap + kc + 4);
    i32x4 wh0 = *(const i32x4*)(Wh0 + kc);
    i32x4 wh1 = *(const i32x4*)(Wh1 + kc);
    i32x4 wl0 = *(const i32x4*)(Wl0 + kc);
    i32x4 wl1 = *(const i32x4*)(Wl1 + kc);
    i32x4 ah, al;
    split8(a0, a1, ah, al);
    // (Ah+Al)*(Wh+Wl) minus negligible Al*Wl: 3 terms per tile
    acc0 = mfma_bf16(ah, wh0, acc0);
    acc1 = mfma_bf16(ah, wh1, acc1);
    acc0 = mfma_bf16(al, wh0, acc0);
    acc1 = mfma_bf16(al, wh1, acc1);
    acc0 = mfma_bf16(ah, wl0, acc0);
    acc1 = mfma_bf16(ah, wl1, acc1);
  }

  // logits -> LDS. C/D layout (verified): col=lane&15, row=(lane>>4)*4+reg.
#pragma unroll
  for (int r = 0; r < 4; ++r) {
    const int row = tg * 16 + fko * 4 + r;
    L[row * LP + eg * 32 + l15] = acc0[r];
    L[row * LP + eg * 32 + 16 + l15] = acc1[r];
  }
  __syncthreads();

  // softmax + top-2: 8 waves x 8 tokens, lane = expert (proven epilogue)
  const int wv8 = tid >> 6;
#pragma unroll
  for (int r = 0; r < 8; ++r) {
    const int lt = wv8 * 8 + r;
    const int tok = bt * BM + lt;
    const float l = L[lt * LP + lane];

    float m = l;
#pragma unroll
    for (int off = 32; off >= 1; off >>= 1) m = fmaxf(m, __shfl_xor(m, off, 64));

    const float e = expf(l - m);
    float sum = e;
#pragma unroll
    for (int off = 32; off >= 1; off >>= 1) sum += __shfl_xor(sum, off, 64);

    const float p = e / sum;
    out[(size_t)tok * NE + lane] = p;

    float m0 = p;
#pragma unroll
    for (int off = 32; off >= 1; off >>= 1) m0 = fmaxf(m0, __shfl_xor(m0, off, 64));
    const unsigned long long b0 = __ballot(p == m0);
    const int i0 = __ffsll(b0) - 1;

    const float pm = (lane == i0) ? -1.f : p;
    float m1 = pm;
#pragma unroll
    for (int off = 32; off >= 1; off >>= 1) m1 = fmaxf(m1, __shfl_xor(m1, off, 64));
    const unsigned long long b1 = __ballot(pm == m1);
    const int i1 = __ffsll(b1) - 1;

    if (lane == 0) {
      float* idxo = out + (size_t)TOKENS * NE + (size_t)tok * 2;
      idxo[0] = (float)i0;
      idxo[1] = (float)i1;
      float* wo = out + (size_t)TOKENS * NE + (size_t)TOKENS * 2 + (size_t)tok * 2;
      const float d = m0 + m1;
      wo[0] = m0 / d;
      wo[1] = m1 / d;
    }
  }
}

extern "C" void kernel_launch(void* const* d_in, const int* in_sizes, int n_in,
                              void* d_out, int out_size, void* d_ws, size_t ws_size,
                              hipStream_t stream) {
  const float* A = (const float*)d_in[0];  // hidden_states [16384, 4096] f32
  const float* W = (const float*)d_in[1];  // gate_weight   [64, 4096] f32
  float* out = (float*)d_out;
  unsigned short* Whi = (unsigned short*)d_ws;          // 512 KiB
  unsigned short* Wlo = Whi + (size_t)NE * HDIM;        // 512 KiB

  convert_w<<<dim3(NE * HDIM / (256 * 8)), 256, 0, stream>>>(W, Whi, Wlo);
  router_mfma<<<dim3(TOKENS / BM), 512, 0, stream>>>(A, Whi, Wlo, out);
}

// Round 6
// 396.140 us; speedup vs baseline: 1.2025x; 1.2025x over previous
//
#include <hip/hip_runtime.h>
#include <math.h>

// B=4, S=4096 -> 16384 tokens; H=4096; E=64; TOP_K=2
#define TOKENS 16384
#define HDIM 4096
#define NE 64

#define BM 64                   // tokens per block
#define BK 32                   // k per LDS tile (one mfma k-step)
#define KSPLIT 4                // K slices -> 1024 blocks = 4 blocks/CU
#define KSLICE (HDIM / KSPLIT)  // 1024
#define NT (KSLICE / BK)        // 32 K-tiles per block
#define WPAD 40                 // LDS row stride in bf16 (80 B -> 2-way banks, free)
#define TSZ (64 * WPAD)         // elems per sub-tile (2560)

typedef float f32x4 __attribute__((ext_vector_type(4)));
typedef int i32x4 __attribute__((ext_vector_type(4)));
typedef __bf16 bf16x8 __attribute__((ext_vector_type(8)));

// f32 -> (hi, lo) bf16 split of 8 elements; 3-term MFMA ~f32 accuracy (verified).
__device__ __forceinline__ void split8(f32x4 v0, f32x4 v1, i32x4& h, i32x4& l) {
  float x[8];
#pragma unroll
  for (int j = 0; j < 4; ++j) { x[j] = v0[j]; x[4 + j] = v1[j]; }
  union { unsigned short u[8]; i32x4 v; } H, L;
#pragma unroll
  for (int j = 0; j < 8; ++j) {
    __bf16 hb = (__bf16)x[j];
    H.u[j] = __builtin_bit_cast(unsigned short, hb);
    L.u[j] = __builtin_bit_cast(unsigned short, (__bf16)(x[j] - (float)hb));
  }
  h = H.v; l = L.v;
}

__device__ __forceinline__ f32x4 mfma_bf16(i32x4 a, i32x4 b, f32x4 c) {
  return __builtin_amdgcn_mfma_f32_16x16x32_bf16(
      __builtin_bit_cast(bf16x8, a), __builtin_bit_cast(bf16x8, b), c, 0, 0, 0);
}

// Pre-split W (64x4096 f32 -> bf16 hi/lo in workspace). ~2 us once. (verified)
__global__ __launch_bounds__(256) void convert_w(const float* __restrict__ W,
                                                 unsigned short* __restrict__ Wh,
                                                 unsigned short* __restrict__ Wl) {
  const int i = (blockIdx.x * 256 + threadIdx.x) * 8;
  f32x4 v0 = *(const f32x4*)(W + i);
  f32x4 v1 = *(const f32x4*)(W + i + 4);
  i32x4 h, l;
  split8(v0, v1, h, l);
  *(i32x4*)(Wh + i) = h;
  *(i32x4*)(Wl + i) = l;
}

// GEMM partials: P[ks][tok][e]. 1024 blocks x 256 thr -> 4 blocks/CU,
// 16 waves/CU (the round-5 lesson: 1 block/CU lockstep was the ~140us wall).
// Verified round-2/3 structure scaled to BK=32: LDS double-buffer, 2-deep
// register prefetch, ONE barrier per tile. Row stride 40 bf16 (80 B) gives
// 2-way bank access (free) for both staging writes and b128 fragment reads.
// Wave tg owns 16 tokens x all 64 experts: per tile 10 b128 reads, 12 MFMA.
__global__ __launch_bounds__(256, 4) void router_gemm(const float* __restrict__ A,
                                                      const unsigned short* __restrict__ Wh,
                                                      const unsigned short* __restrict__ Wl,
                                                      float* __restrict__ P) {
  __shared__ __align__(16) unsigned short smem[2 * 4 * TSZ];  // 40 KiB
  unsigned short* buf0 = smem;            // [Ah|Al|Wh|Wl] sub-tiles (5 KiB each)
  unsigned short* buf1 = smem + 4 * TSZ;

  const int tid = threadIdx.x;
  const int bt = blockIdx.x;   // token tile
  const int ks = blockIdx.y;   // K slice

  // staging map: row = tid>>2 (0..63), chunk = tid&3 (8 elems each)
  const int srow = tid >> 2;
  const int sc = tid & 3;
  const int soff = srow * WPAD + sc * 8;

  const float* Ab = A + (size_t)(bt * BM + srow) * HDIM + ks * KSLICE + sc * 8;
  const unsigned short* Whb = Wh + (size_t)srow * HDIM + ks * KSLICE + sc * 8;
  const unsigned short* Wlb = Wl + (size_t)srow * HDIM + ks * KSLICE + sc * 8;

  // fragment map: wave tg -> 16-token group; all 4 expert tiles per wave
  const int lane = tid & 63;
  const int tg = tid >> 6;
  const int l15 = lane & 15;
  const int fko = lane >> 4;  // k-subgroup 0..3
  const int aoff = (tg * 16 + l15) * WPAD + fko * 8;
  const int boff0 = l15 * WPAD + fko * 8;

  f32x4 acc[4];
#pragma unroll
  for (int e = 0; e < 4; ++e) acc[e] = (f32x4){0.f, 0.f, 0.f, 0.f};

  // 2-tile-deep register prefetch
  f32x4 a0_0, a1_0, a0_1, a1_1;
  i32x4 wh_0, wl_0, wh_1, wl_1;

  auto loadS = [&](int t, f32x4& a0, f32x4& a1, i32x4& wh, i32x4& wl) {
    const int kc = t * BK;
    a0 = *(const f32x4*)(Ab + kc);
    a1 = *(const f32x4*)(Ab + kc + 4);
    wh = *(const i32x4*)(Whb + kc);
    wl = *(const i32x4*)(Wlb + kc);
  };

  auto stage = [&](unsigned short* B, f32x4 a0, f32x4 a1, i32x4 wh, i32x4 wl) {
    i32x4 h, l;
    split8(a0, a1, h, l);
    *(i32x4*)&B[soff] = h;              // Ah
    *(i32x4*)&B[TSZ + soff] = l;        // Al
    *(i32x4*)&B[2 * TSZ + soff] = wh;   // Wh
    *(i32x4*)&B[3 * TSZ + soff] = wl;   // Wl
  };

  auto compute = [&](const unsigned short* B) {
    const unsigned short* AhS = B;
    const unsigned short* AlS = B + TSZ;
    const unsigned short* WhS = B + 2 * TSZ;
    const unsigned short* WlS = B + 3 * TSZ;
    i32x4 ah = *(const i32x4*)&AhS[aoff];
    i32x4 al = *(const i32x4*)&AlS[aoff];
#pragma unroll
    for (int e = 0; e < 4; ++e) {
      i32x4 wh = *(const i32x4*)&WhS[boff0 + e * 16 * WPAD];
      i32x4 wl = *(const i32x4*)&WlS[boff0 + e * 16 * WPAD];
      acc[e] = mfma_bf16(ah, wh, acc[e]);
      acc[e] = mfma_bf16(al, wh, acc[e]);
      acc[e] = mfma_bf16(ah, wl, acc[e]);
    }
  };

  // prologue: tile0 -> buf0; issue tile1 loads
  loadS(0, a0_0, a1_0, wh_0, wl_0);
  stage(buf0, a0_0, a1_0, wh_0, wl_0);
  loadS(1, a0_1, a1_1, wh_1, wl_1);
  __syncthreads();

  for (int t = 0; t < NT; t += 2) {
    compute(buf0);                                     // tile t
    if (t + 2 < NT) loadS(t + 2, a0_0, a1_0, wh_0, wl_0);
    stage(buf1, a0_1, a1_1, wh_1, wl_1);               // tile t+1
    __syncthreads();

    compute(buf1);                                     // tile t+1
    if (t + 3 < NT) loadS(t + 3, a0_1, a1_1, wh_1, wl_1);
    if (t + 2 < NT) stage(buf0, a0_0, a1_0, wh_0, wl_0);  // tile t+2
    __syncthreads();
  }

  // write partials. C/D layout (verified): col=lane&15, row=(lane>>4)*4+reg.
  float* Pb = P + ((size_t)ks * TOKENS + (size_t)bt * BM) * NE;
#pragma unroll
  for (int e = 0; e < 4; ++e)
#pragma unroll
    for (int r = 0; r < 4; ++r)
      Pb[(size_t)(tg * 16 + fko * 4 + r) * NE + e * 16 + l15] = acc[e][r];
}

// Finalize (round-0 verified epilogue, KSPLIT=4): wave = token, lane = expert.
__global__ __launch_bounds__(256) void router_finalize(const float* __restrict__ P,
                                                       float* __restrict__ out) {
  const int lane = threadIdx.x & 63;
  const int wave = threadIdx.x >> 6;
  const int tok = blockIdx.x * 4 + wave;

  float l = 0.f;
#pragma unroll
  for (int s = 0; s < KSPLIT; ++s)
    l += P[((size_t)s * TOKENS + tok) * NE + lane];

  float m = l;
#pragma unroll
  for (int off = 32; off >= 1; off >>= 1) m = fmaxf(m, __shfl_xor(m, off, 64));

  const float e = expf(l - m);
  float sum = e;
#pragma unroll
  for (int off = 32; off >= 1; off >>= 1) sum += __shfl_xor(sum, off, 64);

  const float p = e / sum;
  out[(size_t)tok * NE + lane] = p;

  float m0 = p;
#pragma unroll
  for (int off = 32; off >= 1; off >>= 1) m0 = fmaxf(m0, __shfl_xor(m0, off, 64));
  const unsigned long long b0 = __ballot(p == m0);
  const int i0 = __ffsll(b0) - 1;

  const float pm = (lane == i0) ? -1.f : p;
  float m1 = pm;
#pragma unroll
  for (int off = 32; off >= 1; off >>= 1) m1 = fmaxf(m1, __shfl_xor(m1, off, 64));
  const unsigned long long b1 = __ballot(pm == m1);
  const int i1 = __ffsll(b1) - 1;

  if (lane == 0) {
    float* idxo = out + (size_t)TOKENS * NE + (size_t)tok * 2;
    idxo[0] = (float)i0;
    idxo[1] = (float)i1;
    float* wo = out + (size_t)TOKENS * NE + (size_t)TOKENS * 2 + (size_t)tok * 2;
    const float d = m0 + m1;
    wo[0] = m0 / d;
    wo[1] = m1 / d;
  }
}

extern "C" void kernel_launch(void* const* d_in, const int* in_sizes, int n_in,
                              void* d_out, int out_size, void* d_ws, size_t ws_size,
                              hipStream_t stream) {
  const float* A = (const float*)d_in[0];  // hidden_states [16384, 4096] f32
  const float* W = (const float*)d_in[1];  // gate_weight   [64, 4096] f32
  float* out = (float*)d_out;
  unsigned short* Whi = (unsigned short*)d_ws;          // 512 KiB
  unsigned short* Wlo = Whi + (size_t)NE * HDIM;        // 512 KiB
  float* P = (float*)(Wlo + (size_t)NE * HDIM);         // 16 MiB partials

  convert_w<<<dim3(NE * HDIM / (256 * 8)), 256, 0, stream>>>(W, Whi, Wlo);
  router_gemm<<<dim3(TOKENS / BM, KSPLIT), 256, 0, stream>>>(A, Whi, Wlo, P);
  router_finalize<<<dim3(TOKENS / 4), 256, 0, stream>>>(P, out);
}